// Round 2
// baseline (24348.148 us; speedup 1.0000x reference)
//
#include <hip/hip_runtime.h>

#define B_   128
#define L_   256
#define CIN  512
#define H_   256
#define T_   501
#define E_   30
#define NC   1024   // 256 proj cols + 768 G cols

typedef short short8 __attribute__((ext_vector_type(8)));
typedef float f32x4  __attribute__((ext_vector_type(4)));
typedef _Float16 f16;

__device__ __forceinline__ float bf2f(unsigned short s){ union{unsigned int i;float f;}v; v.i=((unsigned int)s)<<16; return v.f; }
__device__ __forceinline__ unsigned short f2bf(float f){
  union{float f;unsigned int i;}v; v.f=f;
  unsigned int x=v.i;
  return (unsigned short)((x + 0x7fffu + ((x>>16)&1u)) >> 16);
}
// fp16-pair decode from a packed uint
__device__ __forceinline__ float loh(unsigned int u){ union{unsigned int i; f16 h[2];}v; v.i=u; return (float)v.h[0]; }
__device__ __forceinline__ float hih(unsigned int u){ union{unsigned int i; f16 h[2];}v; v.i=u; return (float)v.h[1]; }
__device__ __forceinline__ float fast_tanh(float x){
  float t = __expf(2.f*x);
  return 1.f - 2.f*__builtin_amdgcn_rcpf(t + 1.f);
}
__device__ __forceinline__ float fast_sigm(float x){
  return __builtin_amdgcn_rcpf(1.f + __expf(-x));
}

// ---------------- workspace layout (bytes) ----------------
#define OFF_C    ((size_t)0)                                   // C [B][L][NC] f16 : 67,108,864
#define OFF_WCTH (OFF_C    + (size_t)B_*L_*NC*2)               // WcatT_hi [NC][CIN] bf16 : 1,048,576
#define OFF_WCTL (OFF_WCTH + (size_t)NC*CIN*2)                 // WcatT_lo [NC][CIN] bf16 : 1,048,576
#define OFF_WREC (OFF_WCTL + (size_t)NC*CIN*2)                 // Wrec [256][1024] f16 : 524,288
#define OFF_WOUT (OFF_WREC + (size_t)256*1024*2)               // Wout [256][64] f16 : 32,768
#define OFF_WIHE (OFF_WOUT + (size_t)256*64*2)                 // WiheT [30][768] f32 : 92,160
#define OFF_LC   (OFF_WIHE + (size_t)30*768*4)                 // LC [B][T][4] f32 : 1,026,048

// ---------------- weight repack ----------------
__global__ __launch_bounds__(256) void build_weights(
    const float* __restrict__ W_i2h, const float* __restrict__ W_h2h,
    const float* __restrict__ W_ih,  const float* __restrict__ W_hh,
    const float* __restrict__ W_gen, const float* __restrict__ W_locgen,
    unsigned short* __restrict__ WcatT_hi, unsigned short* __restrict__ WcatT_lo,
    f16* __restrict__ Wrec, f16* __restrict__ Wout, float* __restrict__ WiheT)
{
  int idx = blockIdx.x*256 + threadIdx.x;
  if (idx < 524288) {                       // WcatT[n][c]: n<256 -> W_i2h row n; else W_ih row n-256 (cols 0..511)
    int n = idx >> 9, c = idx & 511;
    float v = (n < 256) ? W_i2h[n*512 + c] : W_ih[(n-256)*542 + c];
    unsigned short hi = f2bf(v);
    WcatT_hi[idx] = hi;
    WcatT_lo[idx] = f2bf(v - bf2f(hi));
    return;
  }
  idx -= 524288;
  if (idx < 262144) {                       // Wrec[j][col]: col<256 -> W_h2h[col][j], else W_hh[col-256][j]
    int j = idx >> 10, col = idx & 1023;
    float v = (col < 256) ? W_h2h[col*256 + j] : W_hh[(col-256)*256 + j];
    Wrec[idx] = (f16)v; return;
  }
  idx -= 262144;
  if (idx < 16384) {                        // Wout[j][c]: c<30 logits, c in [32,36) loc-hidden, else 0
    int j = idx >> 6, c = idx & 63;
    float v = 0.f;
    if (c < 30) v = W_gen[c*256 + j];
    else if (c >= 32 && c < 36) v = W_locgen[(c-32)*768 + j];
    Wout[idx] = (f16)v; return;
  }
  idx -= 16384;
  if (idx < 23040) {                        // WiheT[e][k] = W_ih[k][512+e]
    int e = idx / 768, k = idx - e*768;
    WiheT[idx] = W_ih[k*542 + 512 + e];
  }
}

// ---------------- precompute GEMM, 3-pass split-bf16 (~fp32 exact): C[b] = fea[b] @ Wcat ----------------
__global__ __launch_bounds__(256) void gemm_kernel(
    const float* __restrict__ fea,
    const unsigned short* __restrict__ WcatT_hi,   // [NC][CIN] bf16
    const unsigned short* __restrict__ WcatT_lo,
    f16* __restrict__ Cm)                          // [B][L][NC] fp16
{
  const int b = blockIdx.y;
  const int mt = blockIdx.x & 1, nt = blockIdx.x >> 1;
  const int m0 = mt*128, n0 = nt*128;
  const int tid = threadIdx.x;
  const int w = tid >> 6, lane = tid & 63;
  const int wm = w >> 1, wn = w & 1;
  const int quad = lane >> 4, l16 = lane & 15;

  __shared__ unsigned short AsH[128][40];
  __shared__ unsigned short AsL[128][40];
  __shared__ unsigned short BsH[128][40];
  __shared__ unsigned short BsL[128][40];

  f32x4 acc[4][4];
#pragma unroll
  for (int i=0;i<4;++i)
#pragma unroll
    for (int j=0;j<4;++j) acc[i][j] = (f32x4){0.f,0.f,0.f,0.f};

  const int r = tid >> 1, hf = tid & 1;

  for (int kt = 0; kt < 16; ++kt) {
    const int c0 = kt*32;
    {
      const float* src = fea + ((size_t)b*L_ + (m0+r))*CIN + c0 + hf*16;
      union { unsigned short s[8]; uint4 v; } h0, h1, l0, l1;
#pragma unroll
      for (int q4 = 0; q4 < 4; ++q4) {
        float4 f = ((const float4*)src)[q4];
        unsigned short hx = f2bf(f.x), hy = f2bf(f.y), hz = f2bf(f.z), hw = f2bf(f.w);
        unsigned short lx = f2bf(f.x - bf2f(hx)), ly = f2bf(f.y - bf2f(hy));
        unsigned short lz = f2bf(f.z - bf2f(hz)), lw = f2bf(f.w - bf2f(hw));
        if (q4 < 2) { int o = q4*4;
          h0.s[o]=hx; h0.s[o+1]=hy; h0.s[o+2]=hz; h0.s[o+3]=hw;
          l0.s[o]=lx; l0.s[o+1]=ly; l0.s[o+2]=lz; l0.s[o+3]=lw;
        } else { int o = (q4-2)*4;
          h1.s[o]=hx; h1.s[o+1]=hy; h1.s[o+2]=hz; h1.s[o+3]=hw;
          l1.s[o]=lx; l1.s[o+1]=ly; l1.s[o+2]=lz; l1.s[o+3]=lw;
        }
      }
      *(uint4*)&AsH[r][hf*16]   = h0.v;
      *(uint4*)&AsH[r][hf*16+8] = h1.v;
      *(uint4*)&AsL[r][hf*16]   = l0.v;
      *(uint4*)&AsL[r][hf*16+8] = l1.v;
      const size_t bo = ((size_t)(n0+r))*CIN + c0 + hf*16;
      uint4 bh0 = ((const uint4*)(WcatT_hi + bo))[0];
      uint4 bh1 = ((const uint4*)(WcatT_hi + bo))[1];
      uint4 bl0 = ((const uint4*)(WcatT_lo + bo))[0];
      uint4 bl1 = ((const uint4*)(WcatT_lo + bo))[1];
      *(uint4*)&BsH[r][hf*16]   = bh0;
      *(uint4*)&BsH[r][hf*16+8] = bh1;
      *(uint4*)&BsL[r][hf*16]   = bl0;
      *(uint4*)&BsL[r][hf*16+8] = bl1;
    }
    __syncthreads();
    short8 afH[4], afL[4], bfH[4], bfL[4];
#pragma unroll
    for (int i=0;i<4;++i) {
      afH[i] = *(const short8*)&AsH[wm*64 + i*16 + l16][quad*8];
      afL[i] = *(const short8*)&AsL[wm*64 + i*16 + l16][quad*8];
    }
#pragma unroll
    for (int j=0;j<4;++j) {
      bfH[j] = *(const short8*)&BsH[wn*64 + j*16 + l16][quad*8];
      bfL[j] = *(const short8*)&BsL[wn*64 + j*16 + l16][quad*8];
    }
#pragma unroll
    for (int i=0;i<4;++i)
#pragma unroll
      for (int j=0;j<4;++j) {
        acc[i][j] = __builtin_amdgcn_mfma_f32_16x16x32_bf16(afH[i], bfH[j], acc[i][j], 0, 0, 0);
        acc[i][j] = __builtin_amdgcn_mfma_f32_16x16x32_bf16(afH[i], bfL[j], acc[i][j], 0, 0, 0);
        acc[i][j] = __builtin_amdgcn_mfma_f32_16x16x32_bf16(afL[i], bfH[j], acc[i][j], 0, 0, 0);
      }
    __syncthreads();
  }
#pragma unroll
  for (int i=0;i<4;++i) {
#pragma unroll
    for (int j=0;j<4;++j) {
      const int ml = m0 + wm*64 + i*16 + quad*4;     // row = quad*4+reg
      const int nl = n0 + wn*64 + j*16 + l16;        // col = lane&15
      f16* dst = Cm + ((size_t)b*L_ + ml)*NC + nl;
#pragma unroll
      for (int rg=0; rg<4; ++rg) dst[(size_t)rg*NC] = (f16)acc[i][j][rg];
    }
  }
}

// ---------------- loc branch precompute (fp32): LC[b][t][i] ----------------
__global__ __launch_bounds__(256) void locpre_kernel(
    const float* __restrict__ fea, const float* __restrict__ Wlt,
    const float* __restrict__ blt, const float* __restrict__ Wlg,
    const float* __restrict__ blg, float* __restrict__ LC)
{
  const int b = blockIdx.x, tid = threadIdx.x;
  __shared__ float WT[CIN][4];
  __shared__ float S[L_][4];
  __shared__ float SW[4];
  __shared__ float BLG[4];
  for (int i = tid; i < 4*CIN; i += 256) { int ii = i >> 9, c = i & 511; WT[c][ii] = Wlg[ii*768 + 256 + c]; }
  if (tid < 4) BLG[tid] = blg[tid];
  __syncthreads();
  if (tid < 4) { float s = 0.f; for (int c = 0; c < CIN; ++c) s += WT[c][tid]; SW[tid] = s; }
  {
    const float4* fr = (const float4*)(fea + ((size_t)b*L_ + tid)*CIN);
    float a0=0.f,a1=0.f,a2=0.f,a3=0.f;
    for (int c4 = 0; c4 < CIN/4; ++c4) {
      float4 f = fr[c4]; int c = c4*4;
      a0 += f.x*WT[c][0] + f.y*WT[c+1][0] + f.z*WT[c+2][0] + f.w*WT[c+3][0];
      a1 += f.x*WT[c][1] + f.y*WT[c+1][1] + f.z*WT[c+2][1] + f.w*WT[c+3][1];
      a2 += f.x*WT[c][2] + f.y*WT[c+1][2] + f.z*WT[c+2][2] + f.w*WT[c+3][2];
      a3 += f.x*WT[c][3] + f.y*WT[c+1][3] + f.z*WT[c+2][3] + f.w*WT[c+3][3];
    }
    S[tid][0]=a0; S[tid][1]=a1; S[tid][2]=a2; S[tid][3]=a3;
  }
  __syncthreads();
  for (int t = tid; t < T_; t += 256) {
    const float* wr = Wlt + (size_t)t*L_;
    float a0=0.f,a1=0.f,a2=0.f,a3=0.f;
    for (int l = 0; l < L_; ++l) {
      float wv = wr[l];
      a0 += wv*S[l][0]; a1 += wv*S[l][1]; a2 += wv*S[l][2]; a3 += wv*S[l][3];
    }
    float bb = blt[t];
    size_t o = ((size_t)b*T_ + t)*4;
    LC[o+0] = a0 + bb*SW[0] + BLG[0];
    LC[o+1] = a1 + bb*SW[1] + BLG[1];
    LC[o+2] = a2 + bb*SW[2] + BLG[2];
    LC[o+3] = a3 + bb*SW[3] + BLG[3];
  }
}

// ---------------- persistent per-batch scan: 501 steps, fused outputs ----------------
__global__ __launch_bounds__(512) void scan_kernel(
    const f16* __restrict__ Cm,                // [B][L][NC]: cols 0..255 proj-as-[l][h], 256..1023 G-as-[l][k]
    const f16* __restrict__ Wrec,              // [256 j][1024] : q | gh
    const f16* __restrict__ Wout,              // [256 j][64]   : logits | pad | loc
    const float* __restrict__ WiheT,           // [30][768]
    const float* __restrict__ LC,              // [B][T][4]
    const float* __restrict__ wscore,
    const float* __restrict__ b_h2h, const float* __restrict__ b_ih,
    const float* __restrict__ b_hh,  const float* __restrict__ b_gen,
    float* __restrict__ out)
{
  const int b = blockIdx.x;
  const int tid = threadIdx.x;

  __shared__ float hbuf[H_];
  __shared__ float qbuf[H_];
  __shared__ float ghb[768];
  __shared__ float gib[768];
  __shared__ float ws_s[H_], bh2h_s[H_];
  __shared__ float bih_s[768], bhh_s[768];
  __shared__ float bgen_s[E_];
  __shared__ float e2[2][H_];
  __shared__ float albuf[L_];
  __shared__ float red[8];
  __shared__ float p6[8][64];
  __shared__ float bc[2];
  __shared__ int elem_s;

  for (int i = tid; i < H_; i += 512) { hbuf[i]=0.f; ws_s[i]=wscore[i]; bh2h_s[i]=b_h2h[i]; }
  for (int i = tid; i < 768; i += 512) { bih_s[i]=b_ih[i]; bhh_s[i]=b_hh[i]; }
  if (tid < E_) bgen_s[tid] = b_gen[tid];
  if (tid == 0) elem_s = 0;
  __syncthreads();

  const unsigned int* CrowU = (const unsigned int*)(Cm + (size_t)b*L_*NC);
  const unsigned int* WrecU = (const unsigned int*)Wrec;
  float* outP = out + (size_t)b*T_*E_;
  float* outL = out + (size_t)B_*T_*E_;

  for (int t = 0; t < T_; ++t) {
    // P1: q|gh from h_prev (cols 2tid,2tid+1 of Wrec)
    {
      float a0 = 0.f, a1 = 0.f;
      const unsigned int* wp = WrecU + tid;
#pragma unroll 8
      for (int j = 0; j < H_; ++j) {
        float hv = hbuf[j];
        unsigned int u = wp[j*512];
        a0 += hv*loh(u); a1 += hv*hih(u);
      }
      int c0 = 2*tid;
      if (c0 < H_) { qbuf[c0] = a0 + bh2h_s[c0]; qbuf[c0+1] = a1 + bh2h_s[c0+1]; }
      else { ghb[c0-H_] = a0 + bhh_s[c0-H_]; ghb[c0-H_+1] = a1 + bhh_s[c0-H_+1]; }
    }
    __syncthreads();
    // P2: e[l] = sum_h ws[h]*tanh(proj[l][h]+q[h]); thread = (l, half-of-h)
    {
      int l = tid & 255, hh = tid >> 8;
      const uint4* cp = (const uint4*)(CrowU + (size_t)l*(NC/2) + hh*64);
      float acc = 0.f;
#pragma unroll 4
      for (int ii = 0; ii < 16; ++ii) {
        uint4 u = cp[ii];
        int h0 = hh*128 + ii*8;
        { float x=loh(u.x)+qbuf[h0+0]; acc+=ws_s[h0+0]*fast_tanh(x);
          x=hih(u.x)+qbuf[h0+1]; acc+=ws_s[h0+1]*fast_tanh(x); }
        { float x=loh(u.y)+qbuf[h0+2]; acc+=ws_s[h0+2]*fast_tanh(x);
          x=hih(u.y)+qbuf[h0+3]; acc+=ws_s[h0+3]*fast_tanh(x); }
        { float x=loh(u.z)+qbuf[h0+4]; acc+=ws_s[h0+4]*fast_tanh(x);
          x=hih(u.z)+qbuf[h0+5]; acc+=ws_s[h0+5]*fast_tanh(x); }
        { float x=loh(u.w)+qbuf[h0+6]; acc+=ws_s[h0+6]*fast_tanh(x);
          x=hih(u.w)+qbuf[h0+7]; acc+=ws_s[h0+7]*fast_tanh(x); }
      }
      e2[hh][l] = acc;
    }
    __syncthreads();
    // softmax over l
    float ev = (tid < H_) ? (e2[0][tid] + e2[1][tid]) : -1e30f;
    float mx = ev;
#pragma unroll
    for (int off = 32; off >= 1; off >>= 1) mx = fmaxf(mx, __shfl_xor(mx, off));
    if (tid < H_ && (tid & 63) == 0) red[tid >> 6] = mx;
    __syncthreads();
    float bmax = fmaxf(fmaxf(red[0],red[1]), fmaxf(red[2],red[3]));
    float p = (tid < H_) ? __expf(ev - bmax) : 0.f;
    float sm = p;
#pragma unroll
    for (int off = 32; off >= 1; off >>= 1) sm += __shfl_xor(sm, off);
    if (tid < H_ && (tid & 63) == 0) red[4 + (tid >> 6)] = sm;
    __syncthreads();
    {
      float inv = 1.f / (red[4]+red[5]+red[6]+red[7]);
      if (tid < H_) albuf[tid] = p * inv;
    }
    __syncthreads();
    // P4: gi = G @ alpha + W_ih[:,512+elem] + b_ih  (cols 2tid,2tid+1 of G)
    int elem = elem_s;
    if (tid < 384) {
      float a0 = 0.f, a1 = 0.f;
      const unsigned int* gp = CrowU + 128 + tid;
#pragma unroll 8
      for (int l = 0; l < L_; ++l) {
        float al = albuf[l];
        unsigned int u = gp[l*512];
        a0 += al*loh(u); a1 += al*hih(u);
      }
      int k0 = 2*tid;
      const float* wie = WiheT + elem*768;
      gib[k0]   = a0 + wie[k0]   + bih_s[k0];
      gib[k0+1] = a1 + wie[k0+1] + bih_s[k0+1];
    }
    __syncthreads();
    // P5: GRU gates + h update
    if (tid < H_) {
      int h = tid;
      float r = fast_sigm(gib[h] + ghb[h]);
      float z = fast_sigm(gib[H_+h] + ghb[H_+h]);
      float n = fast_tanh(gib[2*H_+h] + r*ghb[2*H_+h]);
      hbuf[h] = (1.f - z)*n + z*hbuf[h];
    }
    __syncthreads();
    // P6: fused output matvec (30 logits + 4 loc dots, padded to 64 cols)
    {
      int o = tid & 63, js = tid >> 6;
      const f16* wo = Wout + o;
      float acc = 0.f;
#pragma unroll 8
      for (int j = js*32; j < js*32+32; ++j) acc += hbuf[j]*(float)wo[j*64];
      p6[js][o] = acc;
    }
    __syncthreads();
    if (tid < 64) {
      float v = p6[0][tid];
#pragma unroll
      for (int s = 1; s < 8; ++s) v += p6[s][tid];
      p6[0][tid] = v;
    }
    __syncthreads();
    if (tid == 0) {   // argmax (first-max like jnp) + softmax stats
      float best = -1e30f; int bi = 0;
      float lg[E_];
      for (int m = 0; m < E_; ++m) { lg[m] = p6[0][m] + bgen_s[m]; if (lg[m] > best) { best = lg[m]; bi = m; } }
      elem_s = bi;
      float se = 0.f;
      for (int m = 0; m < E_; ++m) se += __expf(lg[m] - best);
      bc[0] = best; bc[1] = 1.f/se;
    }
    __syncthreads();
    if (tid < E_) {
      float lg = p6[0][tid] + bgen_s[tid];
      outP[(size_t)t*E_ + tid] = __expf(lg - bc[0]) * bc[1];
    } else if (tid >= 32 && tid < 36) {
      int i = tid - 32;
      float v = p6[0][tid] + LC[((size_t)b*T_ + t)*4 + i];
      outL[((size_t)b*T_ + t)*4 + i] = fast_sigm(v);
    }
  }
}

extern "C" void kernel_launch(void* const* d_in, const int* in_sizes, int n_in,
                              void* d_out, int out_size, void* d_ws, size_t ws_size,
                              hipStream_t stream) {
  (void)in_sizes; (void)n_in; (void)out_size; (void)ws_size;
  const float* fea    = (const float*)d_in[0];
  const float* W_i2h  = (const float*)d_in[1];
  const float* W_h2h  = (const float*)d_in[2];
  const float* b_h2h  = (const float*)d_in[3];
  const float* wscore = (const float*)d_in[4];
  const float* W_ih   = (const float*)d_in[5];
  const float* W_hh   = (const float*)d_in[6];
  const float* b_ih   = (const float*)d_in[7];
  const float* b_hh   = (const float*)d_in[8];
  const float* W_gen  = (const float*)d_in[9];
  const float* b_gen  = (const float*)d_in[10];
  const float* Wlt    = (const float*)d_in[11];
  const float* blt    = (const float*)d_in[12];
  const float* Wlg    = (const float*)d_in[13];
  const float* blg    = (const float*)d_in[14];

  char* ws = (char*)d_ws;
  f16*            Cm    = (f16*)(ws + OFF_C);
  unsigned short* WcatH = (unsigned short*)(ws + OFF_WCTH);
  unsigned short* WcatL = (unsigned short*)(ws + OFF_WCTL);
  f16*            Wrec  = (f16*)(ws + OFF_WREC);
  f16*            Wout  = (f16*)(ws + OFF_WOUT);
  float*          WiheT = (float*)(ws + OFF_WIHE);
  float*          LCp   = (float*)(ws + OFF_LC);

  build_weights<<<dim3(3226), dim3(256), 0, stream>>>(W_i2h, W_h2h, W_ih, W_hh, W_gen, Wlg,
                                                      WcatH, WcatL, Wrec, Wout, WiheT);
  gemm_kernel<<<dim3(16, B_), dim3(256), 0, stream>>>(fea, WcatH, WcatL, Cm);
  locpre_kernel<<<dim3(B_), dim3(256), 0, stream>>>(fea, Wlt, blt, Wlg, blg, LCp);
  scan_kernel<<<dim3(B_), dim3(512), 0, stream>>>(Cm, Wrec, Wout, WiheT, LCp, wscore,
                                                  b_h2h, b_ih, b_hh, b_gen, (float*)d_out);
}

// Round 3
// 14074.338 us; speedup vs baseline: 1.7300x; 1.7300x over previous
//
#include <hip/hip_runtime.h>

#define B_   128
#define L_   256
#define CIN  512
#define H_   256
#define T_   501
#define E_   30

typedef short short8 __attribute__((ext_vector_type(8)));
typedef float f32x4  __attribute__((ext_vector_type(4)));
typedef _Float16 f16;

__device__ __forceinline__ float bf2f(unsigned short s){ union{unsigned int i;float f;}v; v.i=((unsigned int)s)<<16; return v.f; }
__device__ __forceinline__ unsigned short f2bf(float f){
  union{float f;unsigned int i;}v; v.f=f;
  unsigned int x=v.i;
  return (unsigned short)((x + 0x7fffu + ((x>>16)&1u)) >> 16);
}
__device__ __forceinline__ float fast_tanh(float x){
  float t = __expf(2.f*x);
  return 1.f - 2.f*__builtin_amdgcn_rcpf(t + 1.f);
}
__device__ __forceinline__ float fast_sigm(float x){
  return __builtin_amdgcn_rcpf(1.f + __expf(-x));
}
// fp16-weight * fp32 fma with fp32 accumulate (targets v_fma_mix_f32)
__device__ __forceinline__ float fmam(f16 w, float h, float acc){ return fmaf((float)w, h, acc); }

// ---------------- workspace layout (bytes) ----------------
#define OFF_PROJ ((size_t)0)                                   // proj [B][256 l][256 h] f16 : 16,777,216
#define OFF_G    (OFF_PROJ + (size_t)B_*256*256*2)             // G2 [B][32 lt][768 c][8 li] f16 : 50,331,648
#define OFF_WCTH (OFF_G    + (size_t)B_*32*768*8*2)            // WcatT_hi [1024][512] bf16 : 1,048,576
#define OFF_WCTL (OFF_WCTH + (size_t)1024*512*2)               // WcatT_lo
#define OFF_WREC (OFF_WCTL + (size_t)1024*512*2)               // Wrec2 [32 jt][1024 c][8 ji] f16 : 524,288
#define OFF_WOUT (OFF_WREC + (size_t)32*1024*8*2)              // WoutT [64 o][256 j] f16 : 32,768
#define OFF_WIHE (OFF_WOUT + (size_t)64*256*2)                 // WiheT [30][768] f32 : 92,160
#define OFF_LC   (OFF_WIHE + (size_t)30*768*4)                 // LC [B][T][4] f32 : 1,026,048

// ---------------- weight repack ----------------
__global__ __launch_bounds__(256) void build_weights(
    const float* __restrict__ W_i2h, const float* __restrict__ W_h2h,
    const float* __restrict__ W_ih,  const float* __restrict__ W_hh,
    const float* __restrict__ W_gen, const float* __restrict__ W_locgen,
    unsigned short* __restrict__ WcatT_hi, unsigned short* __restrict__ WcatT_lo,
    f16* __restrict__ Wrec2, f16* __restrict__ WoutT, float* __restrict__ WiheT)
{
  int idx = blockIdx.x*256 + threadIdx.x;
  if (idx < 524288) {                       // WcatT[n][c]: n<256 -> W_i2h row n; else W_ih row n-256 (cols 0..511)
    int n = idx >> 9, c = idx & 511;
    float v = (n < 256) ? W_i2h[n*512 + c] : W_ih[(n-256)*542 + c];
    unsigned short hi = f2bf(v);
    WcatT_hi[idx] = hi;
    WcatT_lo[idx] = f2bf(v - bf2f(hi));
    return;
  }
  idx -= 524288;
  if (idx < 262144) {                       // Wrec2[jt][col][ji] = W[col][j], j = jt*8+ji
    int ji = idx & 7, col = (idx >> 3) & 1023, jt = idx >> 13;
    int j = jt*8 + ji;
    float v = (col < 256) ? W_h2h[col*256 + j] : W_hh[(col-256)*256 + j];
    Wrec2[idx] = (f16)v; return;
  }
  idx -= 262144;
  if (idx < 16384) {                        // WoutT[o][j]: o<30 logits, o in [32,36) loc-hidden, else 0
    int o = idx >> 8, j = idx & 255;
    float v = 0.f;
    if (o < 30) v = W_gen[o*256 + j];
    else if (o >= 32 && o < 36) v = W_locgen[(o-32)*768 + j];
    WoutT[idx] = (f16)v; return;
  }
  idx -= 16384;
  if (idx < 23040) {                        // WiheT[e][k] = W_ih[k][512+e]
    int e = idx / 768, k = idx - e*768;
    WiheT[idx] = W_ih[k*542 + 512 + e];
  }
}

// ---------------- precompute GEMM, 3-pass split-bf16 (~fp32 exact): C[b] = fea[b] @ Wcat ----------------
__global__ __launch_bounds__(256) void gemm_kernel(
    const float* __restrict__ fea,
    const unsigned short* __restrict__ WcatT_hi,   // [1024][512] bf16
    const unsigned short* __restrict__ WcatT_lo,
    f16* __restrict__ ProjH,                       // [B][256][256]
    f16* __restrict__ GH)                          // [B][32][768][8]
{
  const int b = blockIdx.y;
  const int mt = blockIdx.x & 1, nt = blockIdx.x >> 1;
  const int m0 = mt*128, n0 = nt*128;
  const int tid = threadIdx.x;
  const int w = tid >> 6, lane = tid & 63;
  const int wm = w >> 1, wn = w & 1;
  const int quad = lane >> 4, l16 = lane & 15;

  __shared__ unsigned short AsH[128][40];
  __shared__ unsigned short AsL[128][40];
  __shared__ unsigned short BsH[128][40];
  __shared__ unsigned short BsL[128][40];

  f32x4 acc[4][4];
#pragma unroll
  for (int i=0;i<4;++i)
#pragma unroll
    for (int j=0;j<4;++j) acc[i][j] = (f32x4){0.f,0.f,0.f,0.f};

  const int r = tid >> 1, hf = tid & 1;

  for (int kt = 0; kt < 16; ++kt) {
    const int c0 = kt*32;
    {
      const float* src = fea + ((size_t)b*L_ + (m0+r))*CIN + c0 + hf*16;
      union { unsigned short s[8]; uint4 v; } h0, h1, l0, l1;
#pragma unroll
      for (int q4 = 0; q4 < 4; ++q4) {
        float4 f = ((const float4*)src)[q4];
        unsigned short hx = f2bf(f.x), hy = f2bf(f.y), hz = f2bf(f.z), hw = f2bf(f.w);
        unsigned short lx = f2bf(f.x - bf2f(hx)), ly = f2bf(f.y - bf2f(hy));
        unsigned short lz = f2bf(f.z - bf2f(hz)), lw = f2bf(f.w - bf2f(hw));
        if (q4 < 2) { int o = q4*4;
          h0.s[o]=hx; h0.s[o+1]=hy; h0.s[o+2]=hz; h0.s[o+3]=hw;
          l0.s[o]=lx; l0.s[o+1]=ly; l0.s[o+2]=lz; l0.s[o+3]=lw;
        } else { int o = (q4-2)*4;
          h1.s[o]=hx; h1.s[o+1]=hy; h1.s[o+2]=hz; h1.s[o+3]=hw;
          l1.s[o]=lx; l1.s[o+1]=ly; l1.s[o+2]=lz; l1.s[o+3]=lw;
        }
      }
      *(uint4*)&AsH[r][hf*16]   = h0.v;
      *(uint4*)&AsH[r][hf*16+8] = h1.v;
      *(uint4*)&AsL[r][hf*16]   = l0.v;
      *(uint4*)&AsL[r][hf*16+8] = l1.v;
      const size_t bo = ((size_t)(n0+r))*CIN + c0 + hf*16;
      uint4 bh0 = ((const uint4*)(WcatT_hi + bo))[0];
      uint4 bh1 = ((const uint4*)(WcatT_hi + bo))[1];
      uint4 bl0 = ((const uint4*)(WcatT_lo + bo))[0];
      uint4 bl1 = ((const uint4*)(WcatT_lo + bo))[1];
      *(uint4*)&BsH[r][hf*16]   = bh0;
      *(uint4*)&BsH[r][hf*16+8] = bh1;
      *(uint4*)&BsL[r][hf*16]   = bl0;
      *(uint4*)&BsL[r][hf*16+8] = bl1;
    }
    __syncthreads();
    short8 afH[4], afL[4], bfH[4], bfL[4];
#pragma unroll
    for (int i=0;i<4;++i) {
      afH[i] = *(const short8*)&AsH[wm*64 + i*16 + l16][quad*8];
      afL[i] = *(const short8*)&AsL[wm*64 + i*16 + l16][quad*8];
    }
#pragma unroll
    for (int j=0;j<4;++j) {
      bfH[j] = *(const short8*)&BsH[wn*64 + j*16 + l16][quad*8];
      bfL[j] = *(const short8*)&BsL[wn*64 + j*16 + l16][quad*8];
    }
#pragma unroll
    for (int i=0;i<4;++i)
#pragma unroll
      for (int j=0;j<4;++j) {
        acc[i][j] = __builtin_amdgcn_mfma_f32_16x16x32_bf16(afH[i], bfH[j], acc[i][j], 0, 0, 0);
        acc[i][j] = __builtin_amdgcn_mfma_f32_16x16x32_bf16(afH[i], bfL[j], acc[i][j], 0, 0, 0);
        acc[i][j] = __builtin_amdgcn_mfma_f32_16x16x32_bf16(afL[i], bfH[j], acc[i][j], 0, 0, 0);
      }
    __syncthreads();
  }
#pragma unroll
  for (int i=0;i<4;++i) {
#pragma unroll
    for (int j=0;j<4;++j) {
      const int nl = n0 + wn*64 + j*16 + l16;        // col = lane&15
#pragma unroll
      for (int rg=0; rg<4; ++rg) {
        const int ml = m0 + wm*64 + i*16 + quad*4 + rg;   // row = quad*4+reg
        float val = acc[i][j][rg];
        if (nl < 256) ProjH[((size_t)b*256 + ml)*256 + nl] = (f16)val;
        else          GH[(((size_t)b*32 + (ml>>3))*768 + (nl-256))*8 + (ml&7)] = (f16)val;
      }
    }
  }
}

// ---------------- loc branch precompute (fp32): LC[b][t][i] ----------------
__global__ __launch_bounds__(256) void locpre_kernel(
    const float* __restrict__ fea, const float* __restrict__ Wlt,
    const float* __restrict__ blt, const float* __restrict__ Wlg,
    const float* __restrict__ blg, float* __restrict__ LC)
{
  const int b = blockIdx.x, tid = threadIdx.x;
  __shared__ float WT[CIN][4];
  __shared__ float S[L_][4];
  __shared__ float SW[4];
  __shared__ float BLG[4];
  for (int i = tid; i < 4*CIN; i += 256) { int ii = i >> 9, c = i & 511; WT[c][ii] = Wlg[ii*768 + 256 + c]; }
  if (tid < 4) BLG[tid] = blg[tid];
  __syncthreads();
  if (tid < 4) { float s = 0.f; for (int c = 0; c < CIN; ++c) s += WT[c][tid]; SW[tid] = s; }
  {
    const float4* fr = (const float4*)(fea + ((size_t)b*L_ + tid)*CIN);
    float a0=0.f,a1=0.f,a2=0.f,a3=0.f;
    for (int c4 = 0; c4 < CIN/4; ++c4) {
      float4 f = fr[c4]; int c = c4*4;
      a0 += f.x*WT[c][0] + f.y*WT[c+1][0] + f.z*WT[c+2][0] + f.w*WT[c+3][0];
      a1 += f.x*WT[c][1] + f.y*WT[c+1][1] + f.z*WT[c+2][1] + f.w*WT[c+3][1];
      a2 += f.x*WT[c][2] + f.y*WT[c+1][2] + f.z*WT[c+2][2] + f.w*WT[c+3][2];
      a3 += f.x*WT[c][3] + f.y*WT[c+1][3] + f.z*WT[c+2][3] + f.w*WT[c+3][3];
    }
    S[tid][0]=a0; S[tid][1]=a1; S[tid][2]=a2; S[tid][3]=a3;
  }
  __syncthreads();
  for (int t = tid; t < T_; t += 256) {
    const float* wr = Wlt + (size_t)t*L_;
    float a0=0.f,a1=0.f,a2=0.f,a3=0.f;
    for (int l = 0; l < L_; ++l) {
      float wv = wr[l];
      a0 += wv*S[l][0]; a1 += wv*S[l][1]; a2 += wv*S[l][2]; a3 += wv*S[l][3];
    }
    float bb = blt[t];
    size_t o = ((size_t)b*T_ + t)*4;
    LC[o+0] = a0 + bb*SW[0] + BLG[0];
    LC[o+1] = a1 + bb*SW[1] + BLG[1];
    LC[o+2] = a2 + bb*SW[2] + BLG[2];
    LC[o+3] = a3 + bb*SW[3] + BLG[3];
  }
}

// ---------------- persistent per-batch scan: 1024 threads, 501 steps ----------------
__global__ __launch_bounds__(1024, 4) void scan_kernel(
    const uint4* __restrict__ Wrec2,           // [32 jt][1024 c] uint4 (8 halves, j=8jt..8jt+7 of col c)
    const uint4* __restrict__ G2,              // [B][32 lt][768 c] uint4 (8 halves, l=8lt..8lt+7 of col c)
    const f16*  __restrict__ Proj,             // [B][256 l][256 h]
    const uint4* __restrict__ WoutT4,          // [64 o][32] uint4 (8 halves of j)
    const float* __restrict__ WiheT,           // [30][768]
    const float* __restrict__ LC,              // [B][T][4]
    const float* __restrict__ wscore,
    const float* __restrict__ b_h2h, const float* __restrict__ b_ih,
    const float* __restrict__ b_hh,  const float* __restrict__ b_gen,
    float* __restrict__ out)
{
  const int b = blockIdx.x;
  const int tid = threadIdx.x;
  const int wv = tid >> 6, ln = tid & 63;

  __shared__ float hbuf[H_];
  __shared__ float qbuf[H_];
  __shared__ float ghb[768];
  __shared__ float gib[768];
  __shared__ float bh2h_s[H_];
  __shared__ float bih_s[768], bhh_s[768];
  __shared__ float bgen_s[32];
  __shared__ float ebuf[L_];
  __shared__ float albuf[L_];
  __shared__ float red[8];
  __shared__ float p6[16][64];
  __shared__ float bc[2];
  __shared__ int elem_s;

  for (int i = tid; i < H_; i += 1024) { hbuf[i]=0.f; bh2h_s[i]=b_h2h[i]; }
  for (int i = tid; i < 768; i += 1024) { bih_s[i]=b_ih[i]; bhh_s[i]=b_hh[i]; }
  if (tid < 32) bgen_s[tid] = (tid < E_) ? b_gen[tid] : -1e30f;
  if (tid == 0) elem_s = 0;

  // per-lane invariants: w_score slice, Wout slice
  const float4 ws4 = *(const float4*)(wscore + ln*4);
  const int o6 = tid & 63, jr = tid >> 6;
  const uint4 wo0 = WoutT4[o6*32 + jr*2];
  const uint4 wo1 = WoutT4[o6*32 + jr*2 + 1];
  __syncthreads();

  const uint4* gp = G2 + (size_t)b*32*768 + tid;
  const f16*  projB = Proj + (size_t)b*256*256;
  float* outP = out + (size_t)b*T_*E_;
  float* outL = out + (size_t)B_*T_*E_;

  for (int t = 0; t < T_; ++t) {
    // ---- P1: (q|gh)[c] = sum_j Wrec[j][c]*h[j], c = tid ----
    {
      float acc = 0.f;
      const uint4* wp = Wrec2 + tid;
#pragma unroll 8
      for (int jt = 0; jt < 32; ++jt) {
        uint4 u = wp[jt*1024];
        union { uint4 v; f16 h[8]; } W; W.v = u;
        float4 ha = *(const float4*)&hbuf[jt*8];
        float4 hb = *(const float4*)&hbuf[jt*8+4];
        acc = fmam(W.h[0], ha.x, acc); acc = fmam(W.h[1], ha.y, acc);
        acc = fmam(W.h[2], ha.z, acc); acc = fmam(W.h[3], ha.w, acc);
        acc = fmam(W.h[4], hb.x, acc); acc = fmam(W.h[5], hb.y, acc);
        acc = fmam(W.h[6], hb.z, acc); acc = fmam(W.h[7], hb.w, acc);
      }
      if (tid < H_) qbuf[tid] = acc + bh2h_s[tid];
      else ghb[tid - H_] = acc + bhh_s[tid - H_];
    }
    __syncthreads();
    // ---- P2: e[l] = sum_h ws[h]*tanh(proj[l][h]+q[h]); wave per l, lanes over h ----
    {
      float4 q4 = *(const float4*)&qbuf[ln*4];
#pragma unroll 2
      for (int i = 0; i < 16; ++i) {
        int l = wv*16 + i;
        union { uint2 v; f16 h[4]; } P;
        P.v = *(const uint2*)(projB + (size_t)l*256 + ln*4);
        float s;
        s  = ws4.x * fast_tanh((float)P.h[0] + q4.x);
        s += ws4.y * fast_tanh((float)P.h[1] + q4.y);
        s += ws4.z * fast_tanh((float)P.h[2] + q4.z);
        s += ws4.w * fast_tanh((float)P.h[3] + q4.w);
#pragma unroll
        for (int off = 32; off >= 1; off >>= 1) s += __shfl_xor(s, off);
        if (ln == 0) ebuf[l] = s;
      }
    }
    __syncthreads();
    // ---- softmax over l (threads 0..255) ----
    {
      float ev = (tid < L_) ? ebuf[tid] : -1e30f;
      float mx = ev;
#pragma unroll
      for (int off = 32; off >= 1; off >>= 1) mx = fmaxf(mx, __shfl_xor(mx, off));
      if (tid < L_ && ln == 0) red[wv] = mx;
      __syncthreads();
      float bmax = fmaxf(fmaxf(red[0],red[1]), fmaxf(red[2],red[3]));
      float p = (tid < L_) ? __expf(ev - bmax) : 0.f;
      float sm = p;
#pragma unroll
      for (int off = 32; off >= 1; off >>= 1) sm += __shfl_xor(sm, off);
      if (tid < L_ && ln == 0) red[4 + wv] = sm;
      __syncthreads();
      float inv = 1.f / (red[4]+red[5]+red[6]+red[7]);
      if (tid < L_) albuf[tid] = p * inv;
    }
    __syncthreads();
    // ---- P4: gi[c] = sum_l G[l][c]*alpha[l] + Wihe[elem][c] + bih[c], c = tid (<768) ----
    int elem = elem_s;
    if (tid < 768) {
      float acc = 0.f;
#pragma unroll 8
      for (int lt = 0; lt < 32; ++lt) {
        uint4 u = gp[lt*768];
        union { uint4 v; f16 h[8]; } W; W.v = u;
        float4 aa = *(const float4*)&albuf[lt*8];
        float4 ab = *(const float4*)&albuf[lt*8+4];
        acc = fmam(W.h[0], aa.x, acc); acc = fmam(W.h[1], aa.y, acc);
        acc = fmam(W.h[2], aa.z, acc); acc = fmam(W.h[3], aa.w, acc);
        acc = fmam(W.h[4], ab.x, acc); acc = fmam(W.h[5], ab.y, acc);
        acc = fmam(W.h[6], ab.z, acc); acc = fmam(W.h[7], ab.w, acc);
      }
      gib[tid] = acc + WiheT[elem*768 + tid] + bih_s[tid];
    }
    __syncthreads();
    // ---- P5: GRU gates + h update ----
    if (tid < H_) {
      int h = tid;
      float r = fast_sigm(gib[h] + ghb[h]);
      float z = fast_sigm(gib[H_+h] + ghb[H_+h]);
      float n = fast_tanh(gib[2*H_+h] + r*ghb[2*H_+h]);
      hbuf[h] = (1.f - z)*n + z*hbuf[h];
    }
    __syncthreads();
    // ---- P6: output matvec partials (Wout in regs) ----
    {
      union { uint4 v; f16 h[8]; } Wa, Wb; Wa.v = wo0; Wb.v = wo1;
      const float* hb = &hbuf[jr*16];
      float4 h0 = *(const float4*)(hb);
      float4 h1 = *(const float4*)(hb+4);
      float4 h2 = *(const float4*)(hb+8);
      float4 h3 = *(const float4*)(hb+12);
      float acc = 0.f;
      acc = fmam(Wa.h[0], h0.x, acc); acc = fmam(Wa.h[1], h0.y, acc);
      acc = fmam(Wa.h[2], h0.z, acc); acc = fmam(Wa.h[3], h0.w, acc);
      acc = fmam(Wa.h[4], h1.x, acc); acc = fmam(Wa.h[5], h1.y, acc);
      acc = fmam(Wa.h[6], h1.z, acc); acc = fmam(Wa.h[7], h1.w, acc);
      acc = fmam(Wb.h[0], h2.x, acc); acc = fmam(Wb.h[1], h2.y, acc);
      acc = fmam(Wb.h[2], h2.z, acc); acc = fmam(Wb.h[3], h2.w, acc);
      acc = fmam(Wb.h[4], h3.x, acc); acc = fmam(Wb.h[5], h3.y, acc);
      acc = fmam(Wb.h[6], h3.z, acc); acc = fmam(Wb.h[7], h3.w, acc);
      p6[jr][o6] = acc;
    }
    __syncthreads();
    if (tid < 64) {
      float v = p6[0][tid];
#pragma unroll
      for (int s = 1; s < 16; ++s) v += p6[s][tid];
      p6[0][tid] = v;
    }
    __syncthreads();
    if (tid == 0) {   // first-max argmax + softmax stats
      float best = -1e30f; int bi = 0;
      float lg[E_];
      for (int m = 0; m < E_; ++m) { lg[m] = p6[0][m] + bgen_s[m]; if (lg[m] > best) { best = lg[m]; bi = m; } }
      elem_s = bi;
      float se = 0.f;
      for (int m = 0; m < E_; ++m) se += __expf(lg[m] - best);
      bc[0] = best; bc[1] = 1.f/se;
    }
    __syncthreads();
    if (tid < E_) {
      float lg = p6[0][tid] + bgen_s[tid];
      outP[(size_t)t*E_ + tid] = __expf(lg - bc[0]) * bc[1];
    } else if (tid >= 32 && tid < 36) {
      int i = tid - 32;
      float v = p6[0][tid] + LC[((size_t)b*T_ + t)*4 + i];
      outL[((size_t)b*T_ + t)*4 + i] = fast_sigm(v);
    }
  }
}

extern "C" void kernel_launch(void* const* d_in, const int* in_sizes, int n_in,
                              void* d_out, int out_size, void* d_ws, size_t ws_size,
                              hipStream_t stream) {
  (void)in_sizes; (void)n_in; (void)out_size; (void)ws_size;
  const float* fea    = (const float*)d_in[0];
  const float* W_i2h  = (const float*)d_in[1];
  const float* W_h2h  = (const float*)d_in[2];
  const float* b_h2h  = (const float*)d_in[3];
  const float* wscore = (const float*)d_in[4];
  const float* W_ih   = (const float*)d_in[5];
  const float* W_hh   = (const float*)d_in[6];
  const float* b_ih   = (const float*)d_in[7];
  const float* b_hh   = (const float*)d_in[8];
  const float* W_gen  = (const float*)d_in[9];
  const float* b_gen  = (const float*)d_in[10];
  const float* Wlt    = (const float*)d_in[11];
  const float* blt    = (const float*)d_in[12];
  const float* Wlg    = (const float*)d_in[13];
  const float* blg    = (const float*)d_in[14];

  char* ws = (char*)d_ws;
  f16*            ProjH = (f16*)(ws + OFF_PROJ);
  f16*            GH    = (f16*)(ws + OFF_G);
  unsigned short* WcatH = (unsigned short*)(ws + OFF_WCTH);
  unsigned short* WcatL = (unsigned short*)(ws + OFF_WCTL);
  f16*            Wrec2 = (f16*)(ws + OFF_WREC);
  f16*            WoutT = (f16*)(ws + OFF_WOUT);
  float*          WiheT = (float*)(ws + OFF_WIHE);
  float*          LCp   = (float*)(ws + OFF_LC);

  build_weights<<<dim3(3226), dim3(256), 0, stream>>>(W_i2h, W_h2h, W_ih, W_hh, W_gen, Wlg,
                                                      WcatH, WcatL, Wrec2, WoutT, WiheT);
  gemm_kernel<<<dim3(16, B_), dim3(256), 0, stream>>>(fea, WcatH, WcatL, ProjH, GH);
  locpre_kernel<<<dim3(B_), dim3(256), 0, stream>>>(fea, Wlt, blt, Wlg, blg, LCp);
  scan_kernel<<<dim3(B_), dim3(1024), 0, stream>>>((const uint4*)Wrec2, (const uint4*)GH, ProjH,
                                                   (const uint4*)WoutT, WiheT, LCp, wscore,
                                                   b_h2h, b_ih, b_hh, b_gen, (float*)d_out);
}